// Round 3
// baseline (2561.145 us; speedup 1.0000x reference)
//
#include <hip/hip_runtime.h>

// EP model, deviation-space (d-space) formulation, split-bf16 MFMA.
//
// s_k = c_k + d_k with c the free forward chain (exact fixed point).
// Free phase: g0 == 0 bitwise, ep_grads = gb/BETA.
// All relaxation runs on O(beta)-scale deviations d_k:
//   iter0: e3 = beta*(c3-y); d3 = -lr*e3; d2 = -lr*(e3@W2^T); d1 = d2@W1^T
//   iters 1..19:
//     r2 = d2 - d1@W1 ; r3 = d3 - d2@W2
//     d3 = (1-lr*beta)*d3 - lr*r3 - lr*e3
//     d1 = (1-lr)*d1 + lr*(r2@W1^T)
//     d2 = d2 - lr*r2 + lr*(r3@W2^T)
//   final: r2* = d2 - d1@W1 ; r3* = d3 - d2@W2 ; r1* = d1
//   ep0 = -(1/b) x^T d1 ; ep1 = -(1/b) s1^T r2* ; ep2 = -(1/b) s2^T r3*
//   loss = mean(e3^2)/beta^2
//
// O(beta) GEMMs use 2 MFMA products (split A hi/lo x bf16(W)); O(1) GEMMs
// (forward chain, ep) use 3 products. Epilogues (residual formation, state
// updates, hi/lo re-splits) are fused into the GEMM epilogue; independent
// GEMMs are merged into one launch for occupancy (1.5-2 blocks/CU).

typedef float f32x4 __attribute__((ext_vector_type(4)));
typedef __bf16 bf16x8 __attribute__((ext_vector_type(8)));
typedef unsigned short u16;
typedef unsigned int u32;

namespace {

constexpr float LR = 0.5f;
constexpr float BETA = 1e-3f;

__device__ inline void splitbf(float v, u16& h, u16& l) {
  __bf16 hb = (__bf16)v;
  float hf = (float)hb;
  __bf16 lb = (__bf16)(v - hf);
  h = __builtin_bit_cast(u16, hb);
  l = __builtin_bit_cast(u16, lb);
}
__device__ inline u32 pack2(u16 a, u16 b) { return (u32)a | ((u32)b << 16); }

__device__ inline f32x4 MF(bf16x8 a, bf16x8 b, f32x4 c) {
  return __builtin_amdgcn_mfma_f32_16x16x32_bf16(a, b, c, 0, 0, 0);
}

// ---------------------------------------------------------------------------
// NT MFMA GEMM, 64x64 tile, BK=64, 4 waves (wave-tile 32x32), fused epilogue.
// C[m,n] = sum_k A[m,k]*B[n,k];  NP=2: (Ah+Al)*Bh ; NP=3: +Ah*Bl
// role 0: v = alpha*S + c0*E0 + c1v*E1 -> of / (oh,ol)
// role 1: c3=S -> of; e3=beta*(c3-E0[y]) -> of2 + (oh,ol); of3 = -lr*e3 (d3)
// role 2: r3 = E0[d3] - S -> (oh,ol); of[d3] = (1-lr*b)*E0 - lr*r3 - lr*E1[e3]
// ---------------------------------------------------------------------------
struct GemmP {
  const u16 *Ah, *Al, *Bh, *Bl;
  const float *E0, *E1;
  float *of, *of2, *of3;
  u16 *oh, *ol;
  float alpha, c0, c1v;
  int M, N, K, ntn, role;
};

template <int NP>
__global__ __launch_bounds__(256) void gemm_f(GemmP ca, GemmP cb, GemmP cc,
                                              int nb0, int nb01) {
  constexpr int NARR = NP + 1;  // staged arrays: Ah, Al, Bh, (Bl)
  __shared__ u16 lds[2][NARR][64 * 64];
  GemmP c;
  int b = blockIdx.x;
  if (b < nb0) c = ca;
  else if (b < nb01) { c = cb; b -= nb0; }
  else { c = cc; b -= nb01; }
  const int tm = b / c.ntn, tn = b % c.ntn;
  const int tid = threadIdx.x, lane = tid & 63, w = tid >> 6;
  const int K = c.K;

  // ---- staging setup: NARR*512 chunks of 16B; each thread NARR*2 chunks ----
  constexpr int NCH = NARR * 2;
  const u16* gptr[NCH];
  int loff[NCH];
  {
    const u16* bases[4] = {c.Ah, c.Al, c.Bh, c.Bl};
#pragma unroll
    for (int q = 0; q < NCH; ++q) {
      const int g = q * 256 + tid;
      const int arr = g >> 9, ch = g & 511;
      const int row = ch >> 3, sl = ch & 7;
      const int rowbase = (arr < 2 ? tm : tn) << 6;
      gptr[q] = bases[arr] + (size_t)(rowbase + row) * K + sl * 8;
      loff[q] = arr * 8192 + row * 128 + ((sl ^ (row & 7)) << 4);
    }
  }

  // ---- fragment read offsets (within one staged buffer) ----
  const int wm = (w >> 1) << 5, wn = (w & 1) << 5;
  const int fr = lane & 15, fs = lane >> 4;
  int aoff[2][2], boff[2][2];
#pragma unroll
  for (int i = 0; i < 2; ++i)
#pragma unroll
    for (int kk = 0; kk < 2; ++kk) {
      const int ra = wm + i * 16 + fr;
      aoff[i][kk] = ra * 128 + ((((kk << 2) + fs) ^ (ra & 7)) << 4);
      const int rb = wn + i * 16 + fr;
      boff[i][kk] = rb * 128 + ((((kk << 2) + fs) ^ (rb & 7)) << 4);
    }

  // ---- prologue: stage k-step 0 ----
  uint4 st[NCH];
#pragma unroll
  for (int q = 0; q < NCH; ++q) st[q] = *(const uint4*)gptr[q];
  {
    char* lb = (char*)&lds[0][0][0];
#pragma unroll
    for (int q = 0; q < NCH; ++q) *(uint4*)(lb + loff[q]) = st[q];
  }
  __syncthreads();

  f32x4 acc[2][2] = {};
  const int nk = K >> 6;
  int cur = 0;
  for (int s = 0; s < nk; ++s) {
    if (s + 1 < nk) {
#pragma unroll
      for (int q = 0; q < NCH; ++q)
        st[q] = *(const uint4*)(gptr[q] + (size_t)(s + 1) * 64);
    }
    const char* rb = (const char*)&lds[cur][0][0];
    bf16x8 ah[2][2], al[2][2], bh[2][2], bl[2][2];
#pragma unroll
    for (int i = 0; i < 2; ++i)
#pragma unroll
      for (int kk = 0; kk < 2; ++kk) {
        ah[i][kk] = *(const bf16x8*)(rb + aoff[i][kk]);
        al[i][kk] = *(const bf16x8*)(rb + 8192 + aoff[i][kk]);
        bh[i][kk] = *(const bf16x8*)(rb + 16384 + boff[i][kk]);
        if (NP == 3) bl[i][kk] = *(const bf16x8*)(rb + 24576 + boff[i][kk]);
      }
#pragma unroll
    for (int kk = 0; kk < 2; ++kk)
#pragma unroll
      for (int i = 0; i < 2; ++i)
#pragma unroll
        for (int j = 0; j < 2; ++j) {
          acc[i][j] = MF(ah[i][kk], bh[j][kk], acc[i][j]);
          acc[i][j] = MF(al[i][kk], bh[j][kk], acc[i][j]);
          if (NP == 3) acc[i][j] = MF(ah[i][kk], bl[j][kk], acc[i][j]);
        }
    if (s + 1 < nk) {
      char* wb = (char*)&lds[cur ^ 1][0][0];
#pragma unroll
      for (int q = 0; q < NCH; ++q) *(uint4*)(wb + loff[q]) = st[q];
    }
    __syncthreads();
    cur ^= 1;
  }

  // ---- fused epilogue; C/D layout: col=lane&15, row=(lane>>4)*4+reg ----
  const int N = c.N;
#pragma unroll
  for (int i = 0; i < 2; ++i)
#pragma unroll
    for (int j = 0; j < 2; ++j)
#pragma unroll
      for (int r = 0; r < 4; ++r) {
        const int gm = (tm << 6) + wm + i * 16 + (fs << 2) + r;
        const int gn = (tn << 6) + wn + j * 16 + fr;
        const size_t idx = (size_t)gm * N + gn;
        const float t = acc[i][j][r];
        if (c.role == 0) {
          float v = c.alpha * t;
          if (c.E0) v = fmaf(c.c0, c.E0[idx], v);
          if (c.E1) v = fmaf(c.c1v, c.E1[idx], v);
          if (c.of) c.of[idx] = v;
          if (c.oh) {
            u16 h, l;
            splitbf(v, h, l);
            c.oh[idx] = h;
            c.ol[idx] = l;
          }
        } else if (c.role == 1) {
          c.of[idx] = t;                          // c3
          const float e = BETA * (t - c.E0[idx]); // e3 = beta*(c3-y)
          c.of2[idx] = e;
          u16 h, l;
          splitbf(e, h, l);
          c.oh[idx] = h;
          c.ol[idx] = l;
          c.of3[idx] = -LR * e;                   // d3 seed
        } else {
          const float d3o = c.E0[idx];
          const float r3 = d3o - t;
          u16 h, l;
          splitbf(r3, h, l);
          c.oh[idx] = h;
          c.ol[idx] = l;
          c.of[idx] = (1.0f - LR * BETA) * d3o - LR * r3 - LR * c.E1[idx];
        }
      }
}

// ---------------------------------------------------------------------------
// straight split: fp32 -> bf16 hi (+lo), 8 elems/thread
// ---------------------------------------------------------------------------
template <bool WLO>
__global__ void split_s(const float* __restrict__ src, u16* __restrict__ oh,
                        u16* __restrict__ ol, int ngrp) {
  const int g = blockIdx.x * blockDim.x + threadIdx.x;
  if (g >= ngrp) return;
  const int i = g * 8;
  const float4 a = *(const float4*)(src + i);
  const float4 b = *(const float4*)(src + i + 4);
  const float v[8] = {a.x, a.y, a.z, a.w, b.x, b.y, b.z, b.w};
  u16 h[8], l[8];
#pragma unroll
  for (int j = 0; j < 8; ++j) splitbf(v[j], h[j], l[j]);
  *(uint4*)(oh + i) = make_uint4(pack2(h[0], h[1]), pack2(h[2], h[3]),
                                 pack2(h[4], h[5]), pack2(h[6], h[7]));
  if (WLO)
    *(uint4*)(ol + i) = make_uint4(pack2(l[0], l[1]), pack2(l[2], l[3]),
                                   pack2(l[4], l[5]), pack2(l[6], l[7]));
}

// ---------------------------------------------------------------------------
// transpose split: out[c][r] = split(a[r][c] (+ b[r][c])), in R x C row-major
// grid (C/64, R/64)
// ---------------------------------------------------------------------------
template <int OP>  // 0: a, 1: a+b
__global__ __launch_bounds__(256) void split_t(const float* __restrict__ a,
                                               const float* __restrict__ b,
                                               u16* __restrict__ oh,
                                               u16* __restrict__ ol, int R,
                                               int C) {
  __shared__ float tile[64][65];
  const int tid = threadIdx.x;
  const int c0 = blockIdx.x << 6, r0 = blockIdx.y << 6;
#pragma unroll
  for (int q = 0; q < 16; ++q) {
    const int i = q * 256 + tid;
    const int r = i >> 6, cc = i & 63;
    const size_t src = (size_t)(r0 + r) * C + c0 + cc;
    float v = a[src];
    if (OP == 1) v += b[src];
    tile[r][cc] = v;
  }
  __syncthreads();
#pragma unroll
  for (int q = 0; q < 2; ++q) {
    const int g = q * 256 + tid;
    const int oc = g >> 3, os = g & 7;
    u16 h[8], l[8];
#pragma unroll
    for (int j = 0; j < 8; ++j) splitbf(tile[os * 8 + j][oc], h[j], l[j]);
    const size_t dst = (size_t)(c0 + oc) * R + r0 + os * 8;
    *(uint4*)(oh + dst) = make_uint4(pack2(h[0], h[1]), pack2(h[2], h[3]),
                                     pack2(h[4], h[5]), pack2(h[6], h[7]));
    *(uint4*)(ol + dst) = make_uint4(pack2(l[0], l[1]), pack2(l[2], l[3]),
                                     pack2(l[4], l[5]), pack2(l[6], l[7]));
  }
}

// ---------------------------------------------------------------------------
// loss = sum(e3^2) -> partials -> final * inv
// ---------------------------------------------------------------------------
__global__ void loss_sq(const float* __restrict__ e, float* __restrict__ partials,
                        int n) {
  __shared__ float red[256];
  float s = 0.f;
  for (int i = blockIdx.x * 256 + threadIdx.x; i < n; i += gridDim.x * 256)
    s = fmaf(e[i], e[i], s);
  red[threadIdx.x] = s;
  __syncthreads();
  for (int off = 128; off > 0; off >>= 1) {
    if (threadIdx.x < off) red[threadIdx.x] += red[threadIdx.x + off];
    __syncthreads();
  }
  if (threadIdx.x == 0) partials[blockIdx.x] = red[0];
}

__global__ void loss_final(const float* __restrict__ partials,
                           float* __restrict__ o, int np, float inv) {
  __shared__ float red[256];
  float s = 0.f;
  for (int i = threadIdx.x; i < np; i += 256) s += partials[i];
  red[threadIdx.x] = s;
  __syncthreads();
  for (int off = 128; off > 0; off >>= 1) {
    if (threadIdx.x < off) red[threadIdx.x] += red[threadIdx.x + off];
    __syncthreads();
  }
  if (threadIdx.x == 0) o[0] = red[0] * inv;
}

}  // namespace

extern "C" void kernel_launch(void* const* d_in, const int* in_sizes, int n_in,
                              void* d_out, int out_size, void* d_ws, size_t ws_size,
                              hipStream_t stream) {
  const float* x  = (const float*)d_in[0];   // 1024 x 1024
  const float* y  = (const float*)d_in[1];   // 1024 x 512
  const float* W0 = (const float*)d_in[2];   // 1024 x 1024
  const float* W1 = (const float*)d_in[3];   // 1024 x 1024
  const float* W2 = (const float*)d_in[4];   // 1024 x 512
  float* out = (float*)d_out;

  const size_t M1 = 1u << 20;  // 1024*1024
  const size_t M5 = 1u << 19;  // 1024*512

  char* wp = (char*)d_ws;
  auto F = [&](size_t n) { float* p = (float*)wp; wp += n * 4; return p; };
  auto U = [&](size_t n) { u16* p = (u16*)wp; wp += n * 2; return p; };

  float* c1 = F(M1);  float* c2 = F(M1);  float* c3 = F(M5);
  float* e3 = F(M5);  float* d1 = F(M1);  float* d2 = F(M1);
  float* d3 = F(M5);  float* r2f = F(M1); float* r3f = F(M5);
  float* lp = F(1024);

  u16* xh = U(M1);   u16* xl = U(M1);     // reused as r2th/r2tl at end
  u16* xth = U(M1);  u16* xtl = U(M1);
  u16* W0th = U(M1); u16* W0tl = U(M1);   // reused as r1th/r1tl at end
  u16* W1h = U(M1);
  u16* W1th = U(M1); u16* W1tl = U(M1);
  u16* W2h = U(M5);
  u16* W2th = U(M5); u16* W2tl = U(M5);
  u16* c1h = U(M1);  u16* c1l = U(M1);    // reused as s1th/s1tl at end
  u16* c2h = U(M1);  u16* c2l = U(M1);    // reused as s2th/s2tl at end
  u16* d1h = U(M1);  u16* d1l = U(M1);
  u16* d2h = U(M1);  u16* d2l = U(M1);
  u16* e3h = U(M5);  u16* e3l = U(M5);    // reused as r3th/r3tl at end
  u16* r2h = U(M1);  u16* r2l = U(M1);
  u16* r3h = U(M5);  u16* r3l = U(M5);

  float* ep0 = out;
  float* ep1 = out + M1;
  float* ep2 = out + 2 * M1;
  float* lossp = out + 2 * M1 + M5;

  const dim3 blk(256);
  const float IB = -1.0f / BETA;

  auto mk = [](const u16* Ah, const u16* Al, const u16* Bh, const u16* Bl,
               int M, int N, int K, int role, float alpha, float c0, float c1v,
               const float* E0, const float* E1, float* of, u16* oh, u16* ol,
               float* of2, float* of3) {
    GemmP p;
    p.Ah = Ah; p.Al = Al; p.Bh = Bh; p.Bl = Bl;
    p.E0 = E0; p.E1 = E1; p.of = of; p.of2 = of2; p.of3 = of3;
    p.oh = oh; p.ol = ol; p.alpha = alpha; p.c0 = c0; p.c1v = c1v;
    p.M = M; p.N = N; p.K = K; p.ntn = N >> 6; p.role = role;
    return p;
  };

  // ---- one-time operand splits ----
  split_s<true><<<512, blk, 0, stream>>>(x, xh, xl, (int)(M1 / 8));
  split_s<false><<<512, blk, 0, stream>>>(W1, W1h, nullptr, (int)(M1 / 8));
  split_s<false><<<256, blk, 0, stream>>>(W2, W2h, nullptr, (int)(M5 / 8));
  split_t<0><<<dim3(16, 16), blk, 0, stream>>>(x, nullptr, xth, xtl, 1024, 1024);
  split_t<0><<<dim3(16, 16), blk, 0, stream>>>(W0, nullptr, W0th, W0tl, 1024, 1024);
  split_t<0><<<dim3(16, 16), blk, 0, stream>>>(W1, nullptr, W1th, W1tl, 1024, 1024);
  split_t<0><<<dim3(8, 16), blk, 0, stream>>>(W2, nullptr, W2th, W2tl, 1024, 512);

  // ---- forward chain (3-product, fp32-parity) ----
  {
    GemmP p = mk(xh, xl, W0th, W0tl, 1024, 1024, 1024, 0, 1.f, 0.f, 0.f,
                 nullptr, nullptr, c1, c1h, c1l, nullptr, nullptr);
    gemm_f<3><<<256, blk, 0, stream>>>(p, p, p, 256, 256);
  }
  {
    GemmP p = mk(c1h, c1l, W1th, W1tl, 1024, 1024, 1024, 0, 1.f, 0.f, 0.f,
                 nullptr, nullptr, c2, c2h, c2l, nullptr, nullptr);
    gemm_f<3><<<256, blk, 0, stream>>>(p, p, p, 256, 256);
  }
  {  // role 1: c3, e3 (+split), d3 = -lr*e3
    GemmP p = mk(c2h, c2l, W2th, W2tl, 1024, 512, 1024, 1, 1.f, 0.f, 0.f,
                 y, nullptr, c3, e3h, e3l, e3, d3);
    gemm_f<3><<<128, blk, 0, stream>>>(p, p, p, 128, 128);
  }
  loss_sq<<<512, blk, 0, stream>>>(e3, lp, (int)M5);
  loss_final<<<1, blk, 0, stream>>>(lp, lossp, 512,
                                    1.0f / (BETA * BETA * (float)M5));

  // ---- iter 0 (coupled; collapses in d-space) ----
  {  // d2 = -lr * (e3 @ W2^T)
    GemmP p = mk(e3h, e3l, W2h, nullptr, 1024, 1024, 512, 0, -LR, 0.f, 0.f,
                 nullptr, nullptr, d2, d2h, d2l, nullptr, nullptr);
    gemm_f<2><<<256, blk, 0, stream>>>(p, p, p, 256, 256);
  }
  {  // d1 = d2 @ W1^T
    GemmP p = mk(d2h, d2l, W1h, nullptr, 1024, 1024, 1024, 0, 1.f, 0.f, 0.f,
                 nullptr, nullptr, d1, d1h, d1l, nullptr, nullptr);
    gemm_f<2><<<256, blk, 0, stream>>>(p, p, p, 256, 256);
  }

  // ---- iterations 1..19 ----
  for (int it = 1; it < 20; ++it) {
    // merged: r2 = d2 - d1@W1  ||  r3 = d3 - d2@W2 (+ d3 update, role 2)
    GemmP pa = mk(d1h, d1l, W1th, nullptr, 1024, 1024, 1024, 0, -1.f, 1.f, 0.f,
                  d2, nullptr, r2f, r2h, r2l, nullptr, nullptr);
    GemmP pb = mk(d2h, d2l, W2th, nullptr, 1024, 512, 1024, 2, 0.f, 0.f, 0.f,
                  d3, e3, d3, r3h, r3l, nullptr, nullptr);
    gemm_f<2><<<384, blk, 0, stream>>>(pa, pb, pb, 256, 384);
    // merged: d1 = (1-lr)d1 + lr*(r2@W1^T)  ||  d2 = d2 - lr*r2 + lr*(r3@W2^T)
    GemmP pc = mk(r2h, r2l, W1h, nullptr, 1024, 1024, 1024, 0, LR, 1.f - LR,
                  0.f, d1, nullptr, d1, d1h, d1l, nullptr, nullptr);
    GemmP pd = mk(r3h, r3l, W2h, nullptr, 1024, 1024, 512, 0, LR, 1.f, -LR,
                  d2, r2f, d2, d2h, d2l, nullptr, nullptr);
    gemm_f<2><<<512, blk, 0, stream>>>(pc, pd, pd, 256, 512);
  }

  // ---- final residuals (fp32 outs only) ----
  {
    GemmP pa = mk(d1h, d1l, W1th, nullptr, 1024, 1024, 1024, 0, -1.f, 1.f, 0.f,
                  d2, nullptr, r2f, nullptr, nullptr, nullptr, nullptr);
    GemmP pb = mk(d2h, d2l, W2th, nullptr, 1024, 512, 1024, 0, -1.f, 1.f, 0.f,
                  d3, nullptr, r3f, nullptr, nullptr, nullptr, nullptr);
    gemm_f<2><<<384, blk, 0, stream>>>(pa, pb, pb, 256, 384);
  }

  // ---- transposed splits for ep GEMMs (reusing dead regions) ----
  u16 *s1th = c1h, *s1tl = c1l, *s2th = c2h, *s2tl = c2l;
  u16 *r1th = W0th, *r1tl = W0tl, *r2th = xh, *r2tl = xl;
  u16 *r3th = e3h, *r3tl = e3l;
  split_t<1><<<dim3(16, 16), blk, 0, stream>>>(c1, d1, s1th, s1tl, 1024, 1024);
  split_t<1><<<dim3(16, 16), blk, 0, stream>>>(c2, d2, s2th, s2tl, 1024, 1024);
  split_t<0><<<dim3(16, 16), blk, 0, stream>>>(d1, nullptr, r1th, r1tl, 1024, 1024);
  split_t<0><<<dim3(16, 16), blk, 0, stream>>>(r2f, nullptr, r2th, r2tl, 1024, 1024);
  split_t<0><<<dim3(8, 16), blk, 0, stream>>>(r3f, nullptr, r3th, r3tl, 1024, 512);

  // ---- EP weight grads (merged 3-cfg, 3-product): ep = -(1/b) * A^T B ----
  {
    GemmP p0 = mk(xth, xtl, r1th, r1tl, 1024, 1024, 1024, 0, IB, 0.f, 0.f,
                  nullptr, nullptr, ep0, nullptr, nullptr, nullptr, nullptr);
    GemmP p1 = mk(s1th, s1tl, r2th, r2tl, 1024, 1024, 1024, 0, IB, 0.f, 0.f,
                  nullptr, nullptr, ep1, nullptr, nullptr, nullptr, nullptr);
    GemmP p2 = mk(s2th, s2tl, r3th, r3tl, 1024, 512, 1024, 0, IB, 0.f, 0.f,
                  nullptr, nullptr, ep2, nullptr, nullptr, nullptr, nullptr);
    gemm_f<3><<<640, blk, 0, stream>>>(p0, p1, p2, 256, 512);
  }
}

// Round 4
// 988.010 us; speedup vs baseline: 2.5922x; 2.5922x over previous
//
#include <hip/hip_runtime.h>

// EP model, deviation-space formulation, split-bf16 MFMA, global_load_lds
// staging with swizzle baked into global operand storage.
//
// s_k = c_k + d_k with c the free forward chain (exact fixed point).
// iter0: e3 = beta*(c3-y); d3 = -lr*e3; d2 = -lr*(e3@W2^T); d1 = d2@W1^T
// iters 1..19:
//   r2 = d2 - d1@W1 ; r3 = d3 - d2@W2
//   d3 = (1-lr*beta)*d3 - lr*r3 - lr*e3
//   d1 = (1-lr)*d1 + lr*(r2@W1^T) ; d2 = d2 - lr*r2 + lr*(r3@W2^T)
// final: r2* = d2 - d1@W1 ; r3* = d3 - d2@W2
// ep0 = -(1/b) x^T d1 ; ep1 = -(1/b) s1^T r2* ; ep2 = -(1/b) s2^T r3*
// loss = mean(e3^2)/beta^2
//
// All bf16 operand buffers are stored SWIZZLED: within each row's 128B
// window, 16B chunk c is stored at position c ^ (row&7). global_load_lds
// (width 16) copies rows linearly into LDS; ds_read_b128 applies the same
// XOR -> 2-way (free) bank access, no ds_write, no reg round-trip.

typedef float f32x4 __attribute__((ext_vector_type(4)));
typedef __bf16 bf16x8 __attribute__((ext_vector_type(8)));
typedef unsigned short u16;
typedef unsigned int u32;

namespace {

constexpr float LR = 0.5f;
constexpr float BETA = 1e-3f;

__device__ inline void splitbf(float v, u16& h, u16& l) {
  __bf16 hb = (__bf16)v;
  float hf = (float)hb;
  __bf16 lb = (__bf16)(v - hf);
  h = __builtin_bit_cast(u16, hb);
  l = __builtin_bit_cast(u16, lb);
}
__device__ inline u32 pack2(u16 a, u16 b) { return (u32)a | ((u32)b << 16); }

__device__ inline f32x4 MF(bf16x8 a, bf16x8 b, f32x4 c) {
  return __builtin_amdgcn_mfma_f32_16x16x32_bf16(a, b, c, 0, 0, 0);
}

// swizzled column index: 16B chunk within 128B window permuted by row&7
__device__ inline int swzc(int row, int col) {
  return (col & ~63) | ((((col >> 3) & 7) ^ (row & 7)) << 3) | (col & 7);
}

struct GemmP {
  const u16 *Ah, *Al, *Bh, *Bl;
  const float *E0, *E1;
  float *of, *of2, *of3;
  u16 *oh, *ol;
  float alpha, c0, c1v;
  int N, K, ntn, role;
};

// ---------------------------------------------------------------------------
// NT MFMA GEMM, 64x64 tile, BK=64, 4 waves, global_load_lds staging.
// C[m,n] = sum_k A[m,k]*B[n,k];  NP=2: (Ah+Al)*Bh ; NP=3: +Ah*Bl
// role 0: v = alpha*S + c0*E0 + c1v*E1 -> of / (oh,ol swizzled)
// role 1: c3=S -> of; e3=beta*(S-E0) -> of2 + (oh,ol); of3 = -lr*e3
// role 2: r3 = E0 - S -> (oh,ol); of = (1-lr*b)*E0 - lr*r3 - lr*E1
// ---------------------------------------------------------------------------
template <int NP>
__global__ __launch_bounds__(256) void gemm_g(GemmP ca, GemmP cb, GemmP cc,
                                              int nb0, int nb01) {
  constexpr int NARR = NP + 1;   // Ah, Al, Bh, (Bl)
  constexpr int NCH = NARR * 2;  // 1KB wave-loads per wave per k-step
  __shared__ u16 lds[2][NARR][64 * 64];
  GemmP c;
  int b = blockIdx.x;
  if (b < nb0) c = ca;
  else if (b < nb01) { c = cb; b -= nb0; }
  else { c = cc; b -= nb01; }
  const int tm = b / c.ntn, tn = b % c.ntn;
  const int tid = threadIdx.x, lane = tid & 63, w = tid >> 6;
  const int K = c.K;

  // ---- staging setup: per wave NCH 1KB loads (8 rows x 128B each) ----
  const char* gq[NCH];
  int loff[NCH];  // wave-uniform byte offset within one lds buffer
  {
    const u16* bases[4] = {c.Ah, c.Al, c.Bh, c.Bl};
#pragma unroll
    for (int q = 0; q < NCH; ++q) {
      const int kb = q * 4 + w;          // 0 .. NARR*8-1
      const int a = kb >> 3, rb = kb & 7;
      const int row0 = (a < 2 ? tm : tn) << 6;
      gq[q] = (const char*)bases[a] +
              (((size_t)(row0 + rb * 8 + (lane >> 3)) * K) << 1) +
              ((lane & 7) << 4);
      loff[q] = a * 8192 + rb * 1024;
    }
  }

  // ---- fragment read byte offsets (same XOR as storage swizzle) ----
  const int wm = (w >> 1) << 5, wn = (w & 1) << 5;
  const int fr = lane & 15, fs = lane >> 4;
  int aoff[2][2], boff[2][2];
#pragma unroll
  for (int i = 0; i < 2; ++i)
#pragma unroll
    for (int kk = 0; kk < 2; ++kk) {
      const int ra = wm + i * 16 + fr;
      aoff[i][kk] = ra * 128 + ((((kk << 2) + fs) ^ (ra & 7)) << 4);
      const int rb2 = wn + i * 16 + fr;
      boff[i][kk] = rb2 * 128 + ((((kk << 2) + fs) ^ (rb2 & 7)) << 4);
    }

  auto stage = [&](int s, int buf) {
    char* lb = (char*)&lds[buf][0][0];
#pragma unroll
    for (int q = 0; q < NCH; ++q)
      __builtin_amdgcn_global_load_lds(
          (const __attribute__((address_space(1))) unsigned int*)(gq[q] +
                                                                  (size_t)s * 128),
          (__attribute__((address_space(3))) unsigned int*)(lb + loff[q]), 16,
          0, 0);
  };

  f32x4 acc[2][2] = {};
  const int nk = K >> 6;

  stage(0, 0);
  __syncthreads();
  int cur = 0;
  for (int s = 0; s < nk; ++s) {
    if (s + 1 < nk) stage(s + 1, cur ^ 1);
    const char* rb = (const char*)&lds[cur][0][0];
    bf16x8 ah[2][2], al[2][2], bh[2][2], bl[2][2];
#pragma unroll
    for (int i = 0; i < 2; ++i)
#pragma unroll
      for (int kk = 0; kk < 2; ++kk) {
        ah[i][kk] = *(const bf16x8*)(rb + aoff[i][kk]);
        al[i][kk] = *(const bf16x8*)(rb + 8192 + aoff[i][kk]);
        bh[i][kk] = *(const bf16x8*)(rb + 16384 + boff[i][kk]);
        if (NP == 3) bl[i][kk] = *(const bf16x8*)(rb + 24576 + boff[i][kk]);
      }
#pragma unroll
    for (int kk = 0; kk < 2; ++kk)
#pragma unroll
      for (int i = 0; i < 2; ++i)
#pragma unroll
        for (int j = 0; j < 2; ++j) {
          acc[i][j] = MF(ah[i][kk], bh[j][kk], acc[i][j]);
          acc[i][j] = MF(al[i][kk], bh[j][kk], acc[i][j]);
          if (NP == 3) acc[i][j] = MF(ah[i][kk], bl[j][kk], acc[i][j]);
        }
    __syncthreads();  // drains vmcnt (stage) + lgkm; flips buffer
    cur ^= 1;
  }

  // ---- fused epilogue; C/D layout: col=lane&15, row=(lane>>4)*4+reg ----
  const int N = c.N;
#pragma unroll
  for (int i = 0; i < 2; ++i)
#pragma unroll
    for (int j = 0; j < 2; ++j)
#pragma unroll
      for (int r = 0; r < 4; ++r) {
        const int gm = (tm << 6) + wm + i * 16 + (fs << 2) + r;
        const int gn = (tn << 6) + wn + j * 16 + fr;
        const size_t idx = (size_t)gm * N + gn;
        const size_t sidx = (size_t)gm * N + swzc(gm, gn);
        const float t = acc[i][j][r];
        if (c.role == 0) {
          float v = c.alpha * t;
          if (c.E0) v = fmaf(c.c0, c.E0[idx], v);
          if (c.E1) v = fmaf(c.c1v, c.E1[idx], v);
          if (c.of) c.of[idx] = v;
          if (c.oh) {
            u16 h, l;
            splitbf(v, h, l);
            c.oh[sidx] = h;
            c.ol[sidx] = l;
          }
        } else if (c.role == 1) {
          c.of[idx] = t;                           // c3
          const float e = BETA * (t - c.E0[idx]);  // e3
          c.of2[idx] = e;
          u16 h, l;
          splitbf(e, h, l);
          c.oh[sidx] = h;
          c.ol[sidx] = l;
          c.of3[idx] = -LR * e;                    // d3 seed
        } else {
          const float d3o = c.E0[idx];
          const float r3 = d3o - t;
          u16 h, l;
          splitbf(r3, h, l);
          c.oh[sidx] = h;
          c.ol[sidx] = l;
          c.of[idx] = (1.0f - LR * BETA) * d3o - LR * r3 - LR * c.E1[idx];
        }
      }
}

// ---------------------------------------------------------------------------
// straight split: fp32 row-major -> swizzled bf16 hi (+lo); cshift=log2(cols)
// ---------------------------------------------------------------------------
template <bool WLO>
__global__ void split_s(const float* __restrict__ src, u16* __restrict__ oh,
                        u16* __restrict__ ol, int ngrp, int cshift) {
  const int g = blockIdx.x * blockDim.x + threadIdx.x;
  if (g >= ngrp) return;
  const int i = g * 8;
  const int r = i >> cshift;
  const int ci = i & ((1 << cshift) - 1);  // chunk-aligned column
  const float4 a = *(const float4*)(src + i);
  const float4 b = *(const float4*)(src + i + 4);
  const float v[8] = {a.x, a.y, a.z, a.w, b.x, b.y, b.z, b.w};
  u16 h[8], l[8];
#pragma unroll
  for (int j = 0; j < 8; ++j) splitbf(v[j], h[j], l[j]);
  const size_t dst = ((size_t)r << cshift) + (ci & ~63) +
                     ((((ci >> 3) & 7) ^ (r & 7)) << 3);
  *(uint4*)(oh + dst) = make_uint4(pack2(h[0], h[1]), pack2(h[2], h[3]),
                                   pack2(h[4], h[5]), pack2(h[6], h[7]));
  if (WLO)
    *(uint4*)(ol + dst) = make_uint4(pack2(l[0], l[1]), pack2(l[2], l[3]),
                                     pack2(l[4], l[5]), pack2(l[6], l[7]));
}

// ---------------------------------------------------------------------------
// transpose split: out[c][r] = split(a[r][c] (+ b[r][c])); out swizzled.
// in R x C row-major, grid (C/64, R/64)
// ---------------------------------------------------------------------------
template <int OP>  // 0: a, 1: a+b
__global__ __launch_bounds__(256) void split_t(const float* __restrict__ a,
                                               const float* __restrict__ b,
                                               u16* __restrict__ oh,
                                               u16* __restrict__ ol, int R,
                                               int C) {
  __shared__ float tile[64][65];
  const int tid = threadIdx.x;
  const int c0 = blockIdx.x << 6, r0 = blockIdx.y << 6;
#pragma unroll
  for (int q = 0; q < 16; ++q) {
    const int i = q * 256 + tid;
    const int r = i >> 6, cc = i & 63;
    const size_t src = (size_t)(r0 + r) * C + c0 + cc;
    float v = a[src];
    if (OP == 1) v += b[src];
    tile[r][cc] = v;
  }
  __syncthreads();
#pragma unroll
  for (int q = 0; q < 2; ++q) {
    const int g = q * 256 + tid;
    const int oc = g >> 3, os = g & 7;  // out-row c0+oc, chunk os of window r0
    u16 h[8], l[8];
#pragma unroll
    for (int j = 0; j < 8; ++j) splitbf(tile[os * 8 + j][oc], h[j], l[j]);
    const int orow = c0 + oc;
    const size_t dst = (size_t)orow * R + r0 + ((os ^ (orow & 7)) << 3);
    *(uint4*)(oh + dst) = make_uint4(pack2(h[0], h[1]), pack2(h[2], h[3]),
                                     pack2(h[4], h[5]), pack2(h[6], h[7]));
    *(uint4*)(ol + dst) = make_uint4(pack2(l[0], l[1]), pack2(l[2], l[3]),
                                     pack2(l[4], l[5]), pack2(l[6], l[7]));
  }
}

// ---------------------------------------------------------------------------
__global__ void loss_sq(const float* __restrict__ e, float* __restrict__ partials,
                        int n) {
  __shared__ float red[256];
  float s = 0.f;
  for (int i = blockIdx.x * 256 + threadIdx.x; i < n; i += gridDim.x * 256)
    s = fmaf(e[i], e[i], s);
  red[threadIdx.x] = s;
  __syncthreads();
  for (int off = 128; off > 0; off >>= 1) {
    if (threadIdx.x < off) red[threadIdx.x] += red[threadIdx.x + off];
    __syncthreads();
  }
  if (threadIdx.x == 0) partials[blockIdx.x] = red[0];
}

__global__ void loss_final(const float* __restrict__ partials,
                           float* __restrict__ o, int np, float inv) {
  __shared__ float red[256];
  float s = 0.f;
  for (int i = threadIdx.x; i < np; i += 256) s += partials[i];
  red[threadIdx.x] = s;
  __syncthreads();
  for (int off = 128; off > 0; off >>= 1) {
    if (threadIdx.x < off) red[threadIdx.x] += red[threadIdx.x + off];
    __syncthreads();
  }
  if (threadIdx.x == 0) o[0] = red[0] * inv;
}

}  // namespace

extern "C" void kernel_launch(void* const* d_in, const int* in_sizes, int n_in,
                              void* d_out, int out_size, void* d_ws, size_t ws_size,
                              hipStream_t stream) {
  const float* x  = (const float*)d_in[0];   // 1024 x 1024
  const float* y  = (const float*)d_in[1];   // 1024 x 512
  const float* W0 = (const float*)d_in[2];   // 1024 x 1024
  const float* W1 = (const float*)d_in[3];   // 1024 x 1024
  const float* W2 = (const float*)d_in[4];   // 1024 x 512
  float* out = (float*)d_out;

  const size_t M1 = 1u << 20;
  const size_t M5 = 1u << 19;

  char* wp = (char*)d_ws;
  auto F = [&](size_t n) { float* p = (float*)wp; wp += n * 4; return p; };
  auto U = [&](size_t n) { u16* p = (u16*)wp; wp += n * 2; return p; };

  float* c1 = F(M1);  float* c2 = F(M1);  float* c3 = F(M5);
  float* e3 = F(M5);  float* d1 = F(M1);  float* d2 = F(M1);
  float* d3 = F(M5);  float* r2f = F(M1); float* r3f = F(M5);
  float* lp = F(1024);

  u16* xh = U(M1);   u16* xl = U(M1);     // reused as r2th/r2tl at end
  u16* xth = U(M1);  u16* xtl = U(M1);
  u16* W0th = U(M1); u16* W0tl = U(M1);   // reused as r1th/r1tl at end
  u16* W1h = U(M1);
  u16* W1th = U(M1); u16* W1tl = U(M1);
  u16* W2h = U(M5);
  u16* W2th = U(M5); u16* W2tl = U(M5);
  u16* c1h = U(M1);  u16* c1l = U(M1);    // reused as s1th/s1tl at end
  u16* c2h = U(M1);  u16* c2l = U(M1);    // reused as s2th/s2tl at end
  u16* d1h = U(M1);  u16* d1l = U(M1);
  u16* d2h = U(M1);  u16* d2l = U(M1);
  u16* e3h = U(M5);  u16* e3l = U(M5);    // reused as r3th/r3tl at end
  u16* r2h = U(M1);  u16* r2l = U(M1);
  u16* r3h = U(M5);  u16* r3l = U(M5);

  float* ep0 = out;
  float* ep1 = out + M1;
  float* ep2 = out + 2 * M1;
  float* lossp = out + 2 * M1 + M5;

  const dim3 blk(256);
  const float IB = -1.0f / BETA;

  auto mk = [](const u16* Ah, const u16* Al, const u16* Bh, const u16* Bl,
               int N, int K, int role, float alpha, float c0, float c1v,
               const float* E0, const float* E1, float* of, u16* oh, u16* ol,
               float* of2, float* of3) {
    GemmP p;
    p.Ah = Ah; p.Al = Al; p.Bh = Bh; p.Bl = Bl;
    p.E0 = E0; p.E1 = E1; p.of = of; p.of2 = of2; p.of3 = of3;
    p.oh = oh; p.ol = ol; p.alpha = alpha; p.c0 = c0; p.c1v = c1v;
    p.N = N; p.K = K; p.ntn = N >> 6; p.role = role;
    return p;
  };

  // ---- one-time operand splits (swizzled storage) ----
  split_s<true><<<512, blk, 0, stream>>>(x, xh, xl, (int)(M1 / 8), 10);
  split_s<false><<<512, blk, 0, stream>>>(W1, W1h, nullptr, (int)(M1 / 8), 10);
  split_s<false><<<256, blk, 0, stream>>>(W2, W2h, nullptr, (int)(M5 / 8), 9);
  split_t<0><<<dim3(16, 16), blk, 0, stream>>>(x, nullptr, xth, xtl, 1024, 1024);
  split_t<0><<<dim3(16, 16), blk, 0, stream>>>(W0, nullptr, W0th, W0tl, 1024, 1024);
  split_t<0><<<dim3(16, 16), blk, 0, stream>>>(W1, nullptr, W1th, W1tl, 1024, 1024);
  split_t<0><<<dim3(8, 16), blk, 0, stream>>>(W2, nullptr, W2th, W2tl, 1024, 512);

  // ---- forward chain (3-product, fp32-parity) ----
  {
    GemmP p = mk(xh, xl, W0th, W0tl, 1024, 1024, 0, 1.f, 0.f, 0.f,
                 nullptr, nullptr, c1, c1h, c1l, nullptr, nullptr);
    gemm_g<3><<<256, blk, 0, stream>>>(p, p, p, 256, 256);
  }
  {
    GemmP p = mk(c1h, c1l, W1th, W1tl, 1024, 1024, 0, 1.f, 0.f, 0.f,
                 nullptr, nullptr, c2, c2h, c2l, nullptr, nullptr);
    gemm_g<3><<<256, blk, 0, stream>>>(p, p, p, 256, 256);
  }
  {  // role 1: c3, e3 (+split), d3 = -lr*e3
    GemmP p = mk(c2h, c2l, W2th, W2tl, 512, 1024, 1, 1.f, 0.f, 0.f,
                 y, nullptr, c3, e3h, e3l, e3, d3);
    gemm_g<3><<<128, blk, 0, stream>>>(p, p, p, 128, 128);
  }
  loss_sq<<<512, blk, 0, stream>>>(e3, lp, (int)M5);
  loss_final<<<1, blk, 0, stream>>>(lp, lossp, 512,
                                    1.0f / (BETA * BETA * (float)M5));

  // ---- iter 0 (coupled; collapses in d-space) ----
  {  // d2 = -lr * (e3 @ W2^T)
    GemmP p = mk(e3h, e3l, W2h, nullptr, 1024, 512, 0, -LR, 0.f, 0.f,
                 nullptr, nullptr, d2, d2h, d2l, nullptr, nullptr);
    gemm_g<2><<<256, blk, 0, stream>>>(p, p, p, 256, 256);
  }
  {  // d1 = d2 @ W1^T
    GemmP p = mk(d2h, d2l, W1h, nullptr, 1024, 1024, 0, 1.f, 0.f, 0.f,
                 nullptr, nullptr, d1, d1h, d1l, nullptr, nullptr);
    gemm_g<2><<<256, blk, 0, stream>>>(p, p, p, 256, 256);
  }

  // ---- iterations 1..19 ----
  for (int it = 1; it < 20; ++it) {
    GemmP pa = mk(d1h, d1l, W1th, nullptr, 1024, 1024, 0, -1.f, 1.f, 0.f,
                  d2, nullptr, r2f, r2h, r2l, nullptr, nullptr);
    GemmP pb = mk(d2h, d2l, W2th, nullptr, 512, 1024, 2, 0.f, 0.f, 0.f,
                  d3, e3, d3, r3h, r3l, nullptr, nullptr);
    gemm_g<2><<<384, blk, 0, stream>>>(pa, pb, pb, 256, 384);
    GemmP pc = mk(r2h, r2l, W1h, nullptr, 1024, 1024, 0, LR, 1.f - LR, 0.f,
                  d1, nullptr, d1, d1h, d1l, nullptr, nullptr);
    GemmP pd = mk(r3h, r3l, W2h, nullptr, 1024, 512, 0, LR, 1.f, -LR,
                  d2, r2f, d2, d2h, d2l, nullptr, nullptr);
    gemm_g<2><<<512, blk, 0, stream>>>(pc, pd, pd, 256, 512);
  }

  // ---- final residuals (fp32 outs only) ----
  {
    GemmP pa = mk(d1h, d1l, W1th, nullptr, 1024, 1024, 0, -1.f, 1.f, 0.f,
                  d2, nullptr, r2f, nullptr, nullptr, nullptr, nullptr);
    GemmP pb = mk(d2h, d2l, W2th, nullptr, 512, 1024, 0, -1.f, 1.f, 0.f,
                  d3, nullptr, r3f, nullptr, nullptr, nullptr, nullptr);
    gemm_g<2><<<384, blk, 0, stream>>>(pa, pb, pb, 256, 384);
  }

  // ---- transposed splits for ep GEMMs (reusing dead regions) ----
  u16 *s1th = c1h, *s1tl = c1l, *s2th = c2h, *s2tl = c2l;
  u16 *r1th = W0th, *r1tl = W0tl, *r2th = xh, *r2tl = xl;
  u16 *r3th = e3h, *r3tl = e3l;
  split_t<1><<<dim3(16, 16), blk, 0, stream>>>(c1, d1, s1th, s1tl, 1024, 1024);
  split_t<1><<<dim3(16, 16), blk, 0, stream>>>(c2, d2, s2th, s2tl, 1024, 1024);
  split_t<0><<<dim3(16, 16), blk, 0, stream>>>(d1, nullptr, r1th, r1tl, 1024, 1024);
  split_t<0><<<dim3(16, 16), blk, 0, stream>>>(r2f, nullptr, r2th, r2tl, 1024, 1024);
  split_t<0><<<dim3(8, 16), blk, 0, stream>>>(r3f, nullptr, r3th, r3tl, 1024, 512);

  // ---- EP weight grads (merged, 3-product): ep = -(1/b) * A^T B ----
  {
    GemmP p0 = mk(xth, xtl, r1th, r1tl, 1024, 1024, 0, IB, 0.f, 0.f,
                  nullptr, nullptr, ep0, nullptr, nullptr, nullptr, nullptr);
    GemmP p1 = mk(s1th, s1tl, r2th, r2tl, 1024, 1024, 0, IB, 0.f, 0.f,
                  nullptr, nullptr, ep1, nullptr, nullptr, nullptr, nullptr);
    GemmP p2 = mk(s2th, s2tl, r3th, r3tl, 512, 1024, 0, IB, 0.f, 0.f,
                  nullptr, nullptr, ep2, nullptr, nullptr, nullptr, nullptr);
    gemm_g<3><<<640, blk, 0, stream>>>(p0, p1, p2, 256, 512);
  }
}